// Round 1
// baseline (744.997 us; speedup 1.0000x reference)
//
#include <hip/hip_runtime.h>
#include <hip/hip_bf16.h>
#include <cstdint>
#include <cstddef>

// ---------------------------------------------------------------------------
// IPAttnProcessor: out = (softmax(QK^T)V + softmax(QKip^T)Vip) @ Wo + bo + residual
// B=8 SQ=4096 C=1280 CAD=2048 H=20 D=64 TXT=77 NT=4 IP_SCALE=1
// Strategy: bf16 MFMA GEMMs (m97 128^2-tile structure) + fused tiny-K attention.
// ---------------------------------------------------------------------------

typedef __bf16 bf16_t;
typedef __bf16 bf16x8 __attribute__((ext_vector_type(8)));
typedef __bf16 bf16x4 __attribute__((ext_vector_type(4)));
typedef float  f32x4  __attribute__((ext_vector_type(4)));
typedef unsigned int u32x4 __attribute__((ext_vector_type(4)));

using as3_void  = __attribute__((address_space(3))) void;
using as1_cvoid = const __attribute__((address_space(1))) void;

#define TXT_ 77

__device__ __forceinline__ bf16x8 ld16(const void* p) {
  u32x4 v = *(const u32x4*)p;
  return __builtin_bit_cast(bf16x8, v);
}

// ---------------------------------------------------------------------------
// GEMM: C[M,N] = A[M,K] (bf16, row-major) @ Bt[N,K]^T (bf16, row-major N x K)
// 128x128 tile, BK=32, 256 threads (2x2 waves, each 64x64 = 4x4 mfma frags).
// A/B staged via global_load_lds(16B) with XOR swizzle (<=2-way bank conflicts).
// EPI=0: store bf16. EPI=1: store f32 + bias[col] + residual[row,col].
// ---------------------------------------------------------------------------
template <int EPI>
__global__ __launch_bounds__(256, 2)
void gemm_bt(const bf16_t* __restrict__ A, const bf16_t* __restrict__ Bt,
             void* __restrict__ Cout, int M, int N, int K,
             const float* __restrict__ bias, const float* __restrict__ residual)
{
  (void)M;
  __shared__ __align__(16) char smem[2][16384]; // per buf: A tile 8KB + B tile 8KB
  const int tid  = threadIdx.x;
  const int lane = tid & 63;
  const int wid  = tid >> 6;
  const int wm = wid >> 1, wn = wid & 1;
  const long bm = (long)blockIdx.x * 128;
  const long bn = (long)blockIdx.y * 128;

  f32x4 acc[4][4] = {};

  // staging: chunk c (1KB = 16 rows x 64B); lane writes 16B at row c*16+(l>>2), kb=(l&3)
  // LDS(row,kb) holds global k-block kb ^ g(row), g(row)=(row&3)^((row>>2)&3)
  const int srow = lane >> 2;
  const int skb  = (lane & 3) ^ (((lane >> 2) ^ (lane >> 4)) & 3);
  const int NT = K >> 5;

  auto stage = [&](int buf, int kt) {
    const int k0 = kt << 5;
#pragma unroll
    for (int cc = 0; cc < 2; ++cc) {
      const int c = wid + cc * 4;
      const bf16_t* ga = A + (bm + c * 16 + srow) * (long)K + (k0 + skb * 8);
      __builtin_amdgcn_global_load_lds((as1_cvoid*)ga,
                                       (as3_void*)(&smem[buf][c * 1024]), 16, 0, 0);
      const bf16_t* gb = Bt + (bn + c * 16 + srow) * (long)K + (k0 + skb * 8);
      __builtin_amdgcn_global_load_lds((as1_cvoid*)gb,
                                       (as3_void*)(&smem[buf][8192 + c * 1024]), 16, 0, 0);
    }
  };

  // fragment read: logical kb = lane>>4, physical kb = logical ^ g(row)
  const int rkb    = (((lane >> 4) ^ (lane & 3) ^ ((lane >> 2) & 3)) & 3) << 4;
  const int rrow_a = wm * 64 + (lane & 15);
  const int rrow_b = wn * 64 + (lane & 15);

  stage(0, 0);
  int cur = 0;
  for (int t = 0; t < NT; ++t) {
    __syncthreads(); // drains vmcnt: buf[cur] staged; prev ds_reads done
    if (t + 1 < NT) stage(cur ^ 1, t + 1);
    const char* sa = smem[cur];
    const char* sb = smem[cur] + 8192;
    bf16x8 af[4], bfv[4];
#pragma unroll
    for (int m = 0; m < 4; ++m)
      af[m] = ld16(sa + (rrow_a + m * 16) * 64 + rkb);
#pragma unroll
    for (int n = 0; n < 4; ++n)
      bfv[n] = ld16(sb + (rrow_b + n * 16) * 64 + rkb);
#pragma unroll
    for (int m = 0; m < 4; ++m)
#pragma unroll
      for (int n = 0; n < 4; ++n)
        acc[m][n] = __builtin_amdgcn_mfma_f32_16x16x32_bf16(af[m], bfv[n], acc[m][n], 0, 0, 0);
    cur ^= 1;
  }

  // C/D layout: col = lane&15, row = (lane>>4)*4 + reg  [m89-verified]
  const int orow0 = wm * 64 + ((lane >> 4) << 2);
  const int ocol0 = wn * 64 + (lane & 15);
#pragma unroll
  for (int m = 0; m < 4; ++m) {
#pragma unroll
    for (int n = 0; n < 4; ++n) {
      const long col = bn + ocol0 + n * 16;
#pragma unroll
      for (int r = 0; r < 4; ++r) {
        const long row = bm + orow0 + m * 16 + r;
        if constexpr (EPI == 0) {
          ((bf16_t*)Cout)[row * N + col] = (bf16_t)acc[m][n][r];
        } else {
          ((float*)Cout)[row * N + col] =
              acc[m][n][r] + bias[col] + residual[row * N + col];
        }
      }
    }
  }
}

// ---------------------------------------------------------------------------
// Fused attention. Block = one (b,h) x 64 q-rows; 4 waves x 16 rows each.
// kvt: [640, 2560] rows b*80+j (j<77 valid): cols [0,1280)=K, [1280,2560)=V
// kvip: [128, 2560] rows b*4+j (j<4 valid)
// P (pre-divided by softmax denom) staged in LDS with 128-key layout:
//   keys 0..76 txt, 77..95 zero, 96..99 ip (x IP_SCALE), 100..127 zero
// so one 4-step PV MFMA accumulation produces out1/l1 + out2/l2.
// ---------------------------------------------------------------------------
__global__ __launch_bounds__(256, 2)
void attn_fused(const bf16_t* __restrict__ q, const bf16_t* __restrict__ kvt,
                const bf16_t* __restrict__ kvip, bf16_t* __restrict__ outp)
{
  __shared__ __align__(16) bf16_t K_lds[80 * 64];    // XOR-swizzled
  __shared__ __align__(16) bf16_t Kip_lds[16 * 64];  // XOR-swizzled
  __shared__ __align__(16) bf16_t Vt_lds[64 * 136];  // V^T [d][key], stride 136
  __shared__ __align__(16) bf16_t P_lds[4][16 * 136];

  const int tid = threadIdx.x, lane = tid & 63, wid = tid >> 6;
  const int h = blockIdx.y, b = blockIdx.z;
  const int kvcol = h << 6;

  for (int idx = tid; idx < 80 * 64; idx += 256) {
    const int j = idx >> 6, d = idx & 63;
    bf16_t v = (bf16_t)0.f;
    if (j < TXT_) v = kvt[(long)(b * 80 + j) * 2560 + kvcol + d];
    K_lds[(j << 6) + (d ^ ((j & 7) << 3))] = v;
  }
  for (int idx = tid; idx < 16 * 64; idx += 256) {
    const int j = idx >> 6, d = idx & 63;
    bf16_t v = (bf16_t)0.f;
    if (j < 4) v = kvip[(long)(b * 4 + j) * 2560 + kvcol + d];
    Kip_lds[(j << 6) + (d ^ ((j & 7) << 3))] = v;
  }
  for (int idx = tid; idx < 128 * 64; idx += 256) {
    const int key = idx >> 6, d = idx & 63;
    bf16_t v = (bf16_t)0.f;
    if (key < TXT_)                    v = kvt[(long)(b * 80 + key) * 2560 + 1280 + kvcol + d];
    else if (key >= 96 && key < 100)   v = kvip[(long)(b * 4 + key - 96) * 2560 + 1280 + kvcol + d];
    Vt_lds[d * 136 + key] = v;
  }
  for (int idx = tid; idx < 4 * 16 * 136; idx += 256)
    (&P_lds[0][0])[idx] = (bf16_t)0.f;
  __syncthreads();

  const int l15  = lane & 15;
  const int dblk = (lane >> 4) << 3;

  // Q fragments (A-operand: row = lane&15, k = (lane>>4)*8 + i)
  const long qrow = (long)b * 4096 + ((long)blockIdx.x << 6) + (wid << 4) + l15;
  const bf16_t* qp = q + qrow * 1280 + kvcol;
  const bf16x8 qf0 = ld16(qp + dblk);
  const bf16x8 qf1 = ld16(qp + 32 + dblk);

  // QK^T over 5 key tiles of 16 (80 keys; >=77 masked)
  f32x4 sc[5];
#pragma unroll
  for (int t = 0; t < 5; ++t) {
    const int j = (t << 4) + l15;
    const bf16x8 k0 = ld16(&K_lds[(j << 6) + (dblk ^ ((j & 7) << 3))]);
    const bf16x8 k1 = ld16(&K_lds[(j << 6) + ((32 + dblk) ^ ((j & 7) << 3))]);
    f32x4 z = {0.f, 0.f, 0.f, 0.f};
    z = __builtin_amdgcn_mfma_f32_16x16x32_bf16(qf0, k0, z, 0, 0, 0);
    z = __builtin_amdgcn_mfma_f32_16x16x32_bf16(qf1, k1, z, 0, 0, 0);
    sc[t] = z;
  }

  const float scale = 0.125f; // 1/sqrt(64)
#pragma unroll
  for (int t = 0; t < 5; ++t) {
    const bool valid = ((t << 4) + l15) < TXT_;
#pragma unroll
    for (int r = 0; r < 4; ++r)
      sc[t][r] = valid ? sc[t][r] * scale : -1e30f;
  }

  // softmax per q-row (row = (lane>>4)*4 + r); keys spread over l&15 x 5 tiles
  const int prow0 = (lane >> 4) << 2;
  bf16_t* myP = &P_lds[wid][0];
#pragma unroll
  for (int r = 0; r < 4; ++r) {
    float m = sc[0][r];
#pragma unroll
    for (int t = 1; t < 5; ++t) m = fmaxf(m, sc[t][r]);
    m = fmaxf(m, __shfl_xor(m, 1));
    m = fmaxf(m, __shfl_xor(m, 2));
    m = fmaxf(m, __shfl_xor(m, 4));
    m = fmaxf(m, __shfl_xor(m, 8));
    float l = 0.f;
#pragma unroll
    for (int t = 0; t < 5; ++t) { const float p = __expf(sc[t][r] - m); sc[t][r] = p; l += p; }
    l += __shfl_xor(l, 1);
    l += __shfl_xor(l, 2);
    l += __shfl_xor(l, 4);
    l += __shfl_xor(l, 8);
    const float inv = 1.f / l;
#pragma unroll
    for (int t = 0; t < 5; ++t)
      myP[(prow0 + r) * 136 + (t << 4) + l15] = (bf16_t)(sc[t][r] * inv);
  }

  // IP attention: 4 keys (cols >=4 masked), separate softmax, keys at 96..99
  {
    const bf16x8 ki0 = ld16(&Kip_lds[(l15 << 6) + (dblk ^ ((l15 & 7) << 3))]);
    const bf16x8 ki1 = ld16(&Kip_lds[(l15 << 6) + ((32 + dblk) ^ ((l15 & 7) << 3))]);
    f32x4 z = {0.f, 0.f, 0.f, 0.f};
    z = __builtin_amdgcn_mfma_f32_16x16x32_bf16(qf0, ki0, z, 0, 0, 0);
    z = __builtin_amdgcn_mfma_f32_16x16x32_bf16(qf1, ki1, z, 0, 0, 0);
    const bool vip = l15 < 4;
#pragma unroll
    for (int r = 0; r < 4; ++r) {
      const float s = vip ? z[r] * scale : -1e30f;
      float m = s;
      m = fmaxf(m, __shfl_xor(m, 1));
      m = fmaxf(m, __shfl_xor(m, 2));
      m = fmaxf(m, __shfl_xor(m, 4));
      m = fmaxf(m, __shfl_xor(m, 8));
      const float p = __expf(s - m);
      float l = p;
      l += __shfl_xor(l, 1);
      l += __shfl_xor(l, 2);
      l += __shfl_xor(l, 4);
      l += __shfl_xor(l, 8);
      myP[(prow0 + r) * 136 + 96 + l15] = (bf16_t)(p * (1.f / l) * 1.0f /*IP_SCALE*/);
    }
  }

  // PV: O[16q x 64d] = P[16q x 128keys] @ V[128keys x 64d], 4 k-steps x 4 n-tiles
  f32x4 o[4] = {};
#pragma unroll
  for (int s = 0; s < 4; ++s) {
    const bf16x8 pa = ld16(&myP[l15 * 136 + (s << 5) + dblk]);
#pragma unroll
    for (int n = 0; n < 4; ++n) {
      const bf16x8 vb = ld16(&Vt_lds[((n << 4) + l15) * 136 + (s << 5) + dblk]);
      o[n] = __builtin_amdgcn_mfma_f32_16x16x32_bf16(pa, vb, o[n], 0, 0, 0);
    }
  }

  const long orow = (long)b * 4096 + ((long)blockIdx.x << 6) + (wid << 4) + prow0;
#pragma unroll
  for (int n = 0; n < 4; ++n)
#pragma unroll
    for (int r = 0; r < 4; ++r)
      outp[(orow + r) * 1280 + kvcol + (n << 4) + l15] = (bf16_t)o[n][r];
}

// ---------------------------------------------------------------------------
// Utility kernels
// ---------------------------------------------------------------------------
__global__ void cvt_bf16(const float* __restrict__ in, bf16_t* __restrict__ out, long n)
{
  const long i = ((long)blockIdx.x * 256 + threadIdx.x) * 4;
  if (i >= n) return;
  const float4 v = *(const float4*)(in + i);
  bf16x4 r;
  r[0] = (bf16_t)v.x; r[1] = (bf16_t)v.y; r[2] = (bf16_t)v.z; r[3] = (bf16_t)v.w;
  *(bf16x4*)(out + i) = r;
}

// in: K x N fp32 -> out: N x K bf16 (row stride ostride)
__global__ void transpose_cvt(const float* __restrict__ in, bf16_t* __restrict__ out,
                              int K, int N, int ostride)
{
  __shared__ float tile[32][33];
  const int k0 = blockIdx.x * 32, n0 = blockIdx.y * 32;
  for (int i = threadIdx.y; i < 32; i += 8)
    tile[i][threadIdx.x] = in[(long)(k0 + i) * N + n0 + threadIdx.x];
  __syncthreads();
  for (int i = threadIdx.y; i < 32; i += 8)
    out[(long)(n0 + i) * ostride + k0 + threadIdx.x] = (bf16_t)tile[threadIdx.x][i];
}

// encoder [8][81][2048] fp32 -> a_txt [640][2048] bf16 (row b*80+j, j<77, pad 0)
//                              a_ip  [128][2048] bf16 (row b*4+j, j<4, pad 0)
__global__ void pack_enc(const float* __restrict__ enc, bf16_t* __restrict__ a_txt,
                         bf16_t* __restrict__ a_ip)
{
  const long t4 = ((long)blockIdx.x * 256 + threadIdx.x) * 4;
  const long NTXT = 640L * 2048;
  bf16x4 r;
  r[0] = r[1] = r[2] = r[3] = (bf16_t)0.f;
  if (t4 < NTXT) {
    const int row = (int)(t4 >> 11), col = (int)(t4 & 2047);
    const int b = row / 80, j = row - b * 80;
    if (j < TXT_) {
      const float4 v = *(const float4*)(enc + (((long)(b * 81 + j)) << 11) + col);
      r[0] = (bf16_t)v.x; r[1] = (bf16_t)v.y; r[2] = (bf16_t)v.z; r[3] = (bf16_t)v.w;
    }
    *(bf16x4*)(a_txt + t4) = r;
  } else {
    const long u = t4 - NTXT;
    const int row = (int)(u >> 11), col = (int)(u & 2047);
    if (row < 32) {
      const int b = row >> 2, j = row & 3;
      const float4 v = *(const float4*)(enc + (((long)(b * 81 + TXT_ + j)) << 11) + col);
      r[0] = (bf16_t)v.x; r[1] = (bf16_t)v.y; r[2] = (bf16_t)v.z; r[3] = (bf16_t)v.w;
    }
    *(bf16x4*)(a_ip + u) = r;
  }
}

// ---------------------------------------------------------------------------
extern "C" void kernel_launch(void* const* d_in, const int* in_sizes, int n_in,
                              void* d_out, int out_size, void* d_ws, size_t ws_size,
                              hipStream_t stream)
{
  (void)in_sizes; (void)n_in; (void)out_size; (void)ws_size;
  const float* hs  = (const float*)d_in[0];
  const float* enc = (const float*)d_in[1];
  const float* Wq  = (const float*)d_in[2];
  const float* Wk  = (const float*)d_in[3];
  const float* Wv  = (const float*)d_in[4];
  const float* Wki = (const float*)d_in[5];
  const float* Wvi = (const float*)d_in[6];
  const float* Wo  = (const float*)d_in[7];
  const float* bo  = (const float*)d_in[8];

  char* ws = (char*)d_ws;
  size_t off = 0;
  auto alloc = [&](size_t bytes) {
    char* p = ws + off;
    off += (bytes + 255) & ~(size_t)255;
    return p;
  };
  bf16_t* buf1   = (bf16_t*)alloc(83886080);  // hs_bf16, reused as attn_out
  bf16_t* qb     = (bf16_t*)alloc(83886080);  // Q (32768 x 1280)
  bf16_t* Wq_t   = (bf16_t*)alloc(3276800);   // 1280 x 1280
  bf16_t* Wo_t   = (bf16_t*)alloc(3276800);
  bf16_t* Wkv_t  = (bf16_t*)alloc(10485760);  // 2560 x 2048
  bf16_t* Wip_t  = (bf16_t*)alloc(10485760);
  bf16_t* a_txt  = (bf16_t*)alloc(2621440);   // 640 x 2048
  bf16_t* a_ip   = (bf16_t*)alloc(524288);    // 128 x 2048
  bf16_t* kv_txt = (bf16_t*)alloc(3276800);   // 640 x 2560
  bf16_t* kv_ip  = (bf16_t*)alloc(655360);    // 128 x 2560

  const dim3 tb(32, 8);
  cvt_bf16<<<40960, 256, 0, stream>>>(hs, buf1, 41943040L);
  transpose_cvt<<<dim3(40, 40), tb, 0, stream>>>(Wq, Wq_t, 1280, 1280, 1280);
  transpose_cvt<<<dim3(40, 40), tb, 0, stream>>>(Wo, Wo_t, 1280, 1280, 1280);
  transpose_cvt<<<dim3(64, 40), tb, 0, stream>>>(Wk, Wkv_t, 2048, 1280, 2048);
  transpose_cvt<<<dim3(64, 40), tb, 0, stream>>>(Wv, Wkv_t + (long)1280 * 2048, 2048, 1280, 2048);
  transpose_cvt<<<dim3(64, 40), tb, 0, stream>>>(Wki, Wip_t, 2048, 1280, 2048);
  transpose_cvt<<<dim3(64, 40), tb, 0, stream>>>(Wvi, Wip_t + (long)1280 * 2048, 2048, 1280, 2048);
  pack_enc<<<1536, 256, 0, stream>>>(enc, a_txt, a_ip);

  // Q = hs_bf16 @ Wq
  gemm_bt<0><<<dim3(256, 10), 256, 0, stream>>>(buf1, Wq_t, qb, 32768, 1280, 1280,
                                                nullptr, nullptr);
  // K|V = txt @ [Wk|Wv]
  gemm_bt<0><<<dim3(5, 20), 256, 0, stream>>>(a_txt, Wkv_t, kv_txt, 640, 2560, 2048,
                                              nullptr, nullptr);
  // Kip|Vip = ip @ [Wk_ip|Wv_ip]
  gemm_bt<0><<<dim3(1, 20), 256, 0, stream>>>(a_ip, Wip_t, kv_ip, 128, 2560, 2048,
                                              nullptr, nullptr);

  // fused dual-softmax attention -> buf1 (hs_bf16 no longer needed)
  attn_fused<<<dim3(64, 20, 8), 256, 0, stream>>>(qb, kv_txt, kv_ip, buf1);

  // out = attn @ Wo + bo + residual (fp32)
  gemm_bt<1><<<dim3(256, 10), 256, 0, stream>>>(buf1, Wo_t, d_out, 32768, 1280, 1280,
                                                bo, hs);
}

// Round 2
// 577.080 us; speedup vs baseline: 1.2910x; 1.2910x over previous
//
#include <hip/hip_runtime.h>
#include <hip/hip_bf16.h>
#include <cstdint>
#include <cstddef>

// ---------------------------------------------------------------------------
// IPAttnProcessor: out = (softmax(QK^T)V + softmax(QKip^T)Vip) @ Wo + bo + residual
// B=8 SQ=4096 C=1280 CAD=2048 H=20 D=64 TXT=77 NT=4 IP_SCALE=1
// bf16 MFMA GEMMs (m97 128^2 structure) + fused tiny-K attention (256 q/block).
// ---------------------------------------------------------------------------

typedef __bf16 bf16_t;
typedef __bf16 bf16x8 __attribute__((ext_vector_type(8)));
typedef __bf16 bf16x4 __attribute__((ext_vector_type(4)));
typedef float  f32x4  __attribute__((ext_vector_type(4)));
typedef unsigned int u32x4 __attribute__((ext_vector_type(4)));

using as3_void  = __attribute__((address_space(3))) void;
using as1_cvoid = const __attribute__((address_space(1))) void;

#define TXT_ 77

__device__ __forceinline__ bf16x8 ld16(const void* p) {
  u32x4 v = *(const u32x4*)p;
  return __builtin_bit_cast(bf16x8, v);
}

// ---------------------------------------------------------------------------
// GEMM: C[M,N] = A[M,K] (bf16 row-major) @ Bt[N,K]^T (bf16 row-major N x K)
// 128x128 tile, BK=32, 256 threads (2x2 waves, 64x64 each).
// EPI=0: bf16 store. EPI=1: f32 + bias[col] + residual[row,col].
// ---------------------------------------------------------------------------
template <int EPI>
__global__ __launch_bounds__(256, 2)
void gemm_bt(const bf16_t* __restrict__ A, const bf16_t* __restrict__ Bt,
             void* __restrict__ Cout, int M, int N, int K,
             const float* __restrict__ bias, const float* __restrict__ residual)
{
  (void)M;
  __shared__ __align__(16) char smem[2][16384];
  const int tid  = threadIdx.x;
  const int lane = tid & 63;
  const int wid  = tid >> 6;
  const int wm = wid >> 1, wn = wid & 1;
  const long bm = (long)blockIdx.x * 128;
  const long bn = (long)blockIdx.y * 128;

  f32x4 acc[4][4] = {};

  const int srow = lane >> 2;
  const int skb  = (lane & 3) ^ (((lane >> 2) ^ (lane >> 4)) & 3);
  const int NT = K >> 5;

  auto stage = [&](int buf, int kt) {
    const int k0 = kt << 5;
#pragma unroll
    for (int cc = 0; cc < 2; ++cc) {
      const int c = wid + cc * 4;
      const bf16_t* ga = A + (bm + c * 16 + srow) * (long)K + (k0 + skb * 8);
      __builtin_amdgcn_global_load_lds((as1_cvoid*)ga,
                                       (as3_void*)(&smem[buf][c * 1024]), 16, 0, 0);
      const bf16_t* gb = Bt + (bn + c * 16 + srow) * (long)K + (k0 + skb * 8);
      __builtin_amdgcn_global_load_lds((as1_cvoid*)gb,
                                       (as3_void*)(&smem[buf][8192 + c * 1024]), 16, 0, 0);
    }
  };

  const int rkb    = (((lane >> 4) ^ (lane & 3) ^ ((lane >> 2) & 3)) & 3) << 4;
  const int rrow_a = wm * 64 + (lane & 15);
  const int rrow_b = wn * 64 + (lane & 15);

  stage(0, 0);
  int cur = 0;
  for (int t = 0; t < NT; ++t) {
    __syncthreads();
    if (t + 1 < NT) stage(cur ^ 1, t + 1);
    const char* sa = smem[cur];
    const char* sb = smem[cur] + 8192;
    bf16x8 af[4], bfv[4];
#pragma unroll
    for (int m = 0; m < 4; ++m)
      af[m] = ld16(sa + (rrow_a + m * 16) * 64 + rkb);
#pragma unroll
    for (int n = 0; n < 4; ++n)
      bfv[n] = ld16(sb + (rrow_b + n * 16) * 64 + rkb);
#pragma unroll
    for (int m = 0; m < 4; ++m)
#pragma unroll
      for (int n = 0; n < 4; ++n)
        acc[m][n] = __builtin_amdgcn_mfma_f32_16x16x32_bf16(af[m], bfv[n], acc[m][n], 0, 0, 0);
    cur ^= 1;
  }

  const int orow0 = wm * 64 + ((lane >> 4) << 2);
  const int ocol0 = wn * 64 + (lane & 15);
#pragma unroll
  for (int m = 0; m < 4; ++m) {
#pragma unroll
    for (int n = 0; n < 4; ++n) {
      const long col = bn + ocol0 + n * 16;
#pragma unroll
      for (int r = 0; r < 4; ++r) {
        const long row = bm + orow0 + m * 16 + r;
        if constexpr (EPI == 0) {
          ((bf16_t*)Cout)[row * N + col] = (bf16_t)acc[m][n][r];
        } else {
          ((float*)Cout)[row * N + col] =
              acc[m][n][r] + bias[col] + residual[row * N + col];
        }
      }
    }
  }
}

// ---------------------------------------------------------------------------
// Fused attention. Block = one (b,h) x 256 q-rows; wave w owns rows [w*64,w*64+64)
// as 4 m-steps of 16. K/V staged ONCE per block (vectorized, XOR-swizzled).
// P (pre-divided by denom) in per-wave LDS [16][128]: keys 0..76 txt, 96..99 ip,
// rest zero -> single 128-key PV accumulation = out_txt + IP_SCALE*out_ip.
// All LDS tiles: power-of-2 row stride, 16B-chunk XOR swizzle (chunk ^= row&7).
// ---------------------------------------------------------------------------
__global__ __launch_bounds__(256, 2)
void attn_fused(const bf16_t* __restrict__ q, const bf16_t* __restrict__ kvt,
                const bf16_t* __restrict__ kvip, bf16_t* __restrict__ outp)
{
  __shared__ __align__(16) bf16_t K_lds[80 * 64];     // [j][d], 128B rows, swz
  __shared__ __align__(16) bf16_t Kip_lds[16 * 64];   // [j][d], swz
  __shared__ __align__(16) bf16_t Vt_lds[64 * 128];   // [d][key], 256B rows, swz
  __shared__ __align__(16) bf16_t P_lds[4][16 * 128]; // per-wave [row][key], swz

  const int tid = threadIdx.x, lane = tid & 63, wid = tid >> 6;
  const int h = blockIdx.y, b = blockIdx.z;
  const int kvcol = h << 6;

  // ---- staging (16B loads; swizzled writes) ----
  for (int idx = tid; idx < 640; idx += 256) {        // K: 80 rows x 8 chunks
    const int j = idx >> 3, c = idx & 7;
    bf16x8 v = {};
    if (j < TXT_) v = ld16(kvt + (long)(b * 80 + j) * 2560 + kvcol + c * 8);
    *(bf16x8*)((char*)K_lds + j * 128 + ((c ^ (j & 7)) << 4)) = v;
  }
  if (tid < 128) {                                    // Kip: 16 rows x 8 chunks
    const int j = tid >> 3, c = tid & 7;
    bf16x8 v = {};
    if (j < 4) v = ld16(kvip + (long)(b * 4 + j) * 2560 + kvcol + c * 8);
    *(bf16x8*)((char*)Kip_lds + j * 128 + ((c ^ (j & 7)) << 4)) = v;
  }
  for (int idx = tid; idx < 1024; idx += 256) {       // V^T: 128 keys x 8 d-chunks
    const int key = idx >> 3, c = idx & 7;
    bf16x8 v = {};
    if (key < TXT_)
      v = ld16(kvt + (long)(b * 80 + key) * 2560 + 1280 + kvcol + c * 8);
    else if (key >= 96 && key < 100)
      v = ld16(kvip + (long)(b * 4 + key - 96) * 2560 + 1280 + kvcol + c * 8);
#pragma unroll
    for (int e = 0; e < 8; ++e) {
      const int d = c * 8 + e;
      *(bf16_t*)((char*)Vt_lds + d * 256 + ((key * 2) ^ ((d & 7) << 4))) = v[e];
    }
  }
  for (int idx = tid; idx < 1024; idx += 256)         // P zero (16KB)
    *(bf16x8*)((char*)P_lds + idx * 16) = (bf16x8){};
  __syncthreads();

  const int l15 = lane & 15, hi = lane >> 4;
  const int dblk = hi << 3;
  const int prow0 = hi << 2;
  const float scale = 0.125f; // 1/sqrt(64)
  char* const pw = (char*)P_lds[wid];

  // preload Q fragments for all 4 m-steps (A-frag: row=lane&15, k=hi*8+i)
  const long qrow0 = (long)b * 4096 + ((long)blockIdx.x << 8) + (wid << 6);
  bf16x8 qf[4][2];
#pragma unroll
  for (int ms = 0; ms < 4; ++ms) {
    const bf16_t* qp = q + (qrow0 + ms * 16 + l15) * 1280 + kvcol;
    qf[ms][0] = ld16(qp + dblk);
    qf[ms][1] = ld16(qp + 32 + dblk);
  }

#pragma unroll
  for (int ms = 0; ms < 4; ++ms) {
    // QK^T over 5 key tiles of 16 (keys >=77 masked after)
    f32x4 sc[5];
#pragma unroll
    for (int t = 0; t < 5; ++t) {
      const int j = (t << 4) + l15;
      const bf16x8 k0 = ld16((char*)K_lds + j * 128 + ((hi ^ (j & 7)) << 4));
      const bf16x8 k1 = ld16((char*)K_lds + j * 128 + (((4 + hi) ^ (j & 7)) << 4));
      f32x4 z = {0.f, 0.f, 0.f, 0.f};
      z = __builtin_amdgcn_mfma_f32_16x16x32_bf16(qf[ms][0], k0, z, 0, 0, 0);
      z = __builtin_amdgcn_mfma_f32_16x16x32_bf16(qf[ms][1], k1, z, 0, 0, 0);
      sc[t] = z;
    }
#pragma unroll
    for (int t = 0; t < 5; ++t) {
      const bool valid = ((t << 4) + l15) < TXT_;
#pragma unroll
      for (int r = 0; r < 4; ++r)
        sc[t][r] = valid ? sc[t][r] * scale : -1e30f;
    }

    // txt softmax per q-row (row=hi*4+r; keys on l15 x 5 tiles), P /= denom
#pragma unroll
    for (int r = 0; r < 4; ++r) {
      float m = sc[0][r];
#pragma unroll
      for (int t = 1; t < 5; ++t) m = fmaxf(m, sc[t][r]);
      m = fmaxf(m, __shfl_xor(m, 1));
      m = fmaxf(m, __shfl_xor(m, 2));
      m = fmaxf(m, __shfl_xor(m, 4));
      m = fmaxf(m, __shfl_xor(m, 8));
      float l = 0.f;
#pragma unroll
      for (int t = 0; t < 5; ++t) { const float p = __expf(sc[t][r] - m); sc[t][r] = p; l += p; }
      l += __shfl_xor(l, 1);
      l += __shfl_xor(l, 2);
      l += __shfl_xor(l, 4);
      l += __shfl_xor(l, 8);
      const float inv = 1.f / l;
      const int row = prow0 + r;
#pragma unroll
      for (int t = 0; t < 5; ++t)
        *(bf16_t*)(pw + row * 256 + ((((t << 4) + l15) * 2) ^ ((row & 7) << 4))) =
            (bf16_t)(sc[t][r] * inv);
    }

    // IP attention (4 keys; l15>=4 masked), separate softmax, keys 96..99
    {
      const bf16x8 ki0 = ld16((char*)Kip_lds + l15 * 128 + ((hi ^ (l15 & 7)) << 4));
      const bf16x8 ki1 = ld16((char*)Kip_lds + l15 * 128 + (((4 + hi) ^ (l15 & 7)) << 4));
      f32x4 z = {0.f, 0.f, 0.f, 0.f};
      z = __builtin_amdgcn_mfma_f32_16x16x32_bf16(qf[ms][0], ki0, z, 0, 0, 0);
      z = __builtin_amdgcn_mfma_f32_16x16x32_bf16(qf[ms][1], ki1, z, 0, 0, 0);
      const bool vip = l15 < 4;
#pragma unroll
      for (int r = 0; r < 4; ++r) {
        const float s = vip ? z[r] * scale : -1e30f;
        float m = s;
        m = fmaxf(m, __shfl_xor(m, 1));
        m = fmaxf(m, __shfl_xor(m, 2));
        m = fmaxf(m, __shfl_xor(m, 4));
        m = fmaxf(m, __shfl_xor(m, 8));
        const float p = __expf(s - m);
        float l = p;
        l += __shfl_xor(l, 1);
        l += __shfl_xor(l, 2);
        l += __shfl_xor(l, 4);
        l += __shfl_xor(l, 8);
        const int row = prow0 + r;
        *(bf16_t*)(pw + row * 256 + (((96 + l15) * 2) ^ ((row & 7) << 4))) =
            (bf16_t)(p * (1.f / l) /* *IP_SCALE==1 */);
      }
    }

    // PV: O[16 x 64] = P[16 x 128] @ Vt^T, 4 k-steps x 4 n-tiles
    f32x4 o[4] = {};
#pragma unroll
    for (int s = 0; s < 4; ++s) {
      const bf16x8 pa =
          ld16(pw + l15 * 256 + ((((s << 2) + hi) << 4) ^ ((l15 & 7) << 4)));
#pragma unroll
      for (int n = 0; n < 4; ++n) {
        const int d = (n << 4) + l15;
        const bf16x8 vb =
            ld16((char*)Vt_lds + d * 256 + ((((s << 2) + hi) << 4) ^ ((d & 7) << 4)));
        o[n] = __builtin_amdgcn_mfma_f32_16x16x32_bf16(pa, vb, o[n], 0, 0, 0);
      }
    }

    const long orow = qrow0 + ms * 16 + prow0;
#pragma unroll
    for (int n = 0; n < 4; ++n)
#pragma unroll
      for (int r = 0; r < 4; ++r)
        outp[(orow + r) * 1280 + kvcol + (n << 4) + l15] = (bf16_t)o[n][r];
  }
}

// ---------------------------------------------------------------------------
// Utility kernels
// ---------------------------------------------------------------------------
__global__ void cvt_bf16(const float* __restrict__ in, bf16_t* __restrict__ out, long n)
{
  const long i = ((long)blockIdx.x * 256 + threadIdx.x) * 4;
  if (i >= n) return;
  const float4 v = *(const float4*)(in + i);
  bf16x4 r;
  r[0] = (bf16_t)v.x; r[1] = (bf16_t)v.y; r[2] = (bf16_t)v.z; r[3] = (bf16_t)v.w;
  *(bf16x4*)(out + i) = r;
}

// in: K x N fp32 -> out: N x K bf16 (row stride ostride)
__global__ void transpose_cvt(const float* __restrict__ in, bf16_t* __restrict__ out,
                              int K, int N, int ostride)
{
  __shared__ float tile[32][33];
  const int k0 = blockIdx.x * 32, n0 = blockIdx.y * 32;
  for (int i = threadIdx.y; i < 32; i += 8)
    tile[i][threadIdx.x] = in[(long)(k0 + i) * N + n0 + threadIdx.x];
  __syncthreads();
  for (int i = threadIdx.y; i < 32; i += 8)
    out[(long)(n0 + i) * ostride + k0 + threadIdx.x] = (bf16_t)tile[threadIdx.x][i];
}

// encoder [8][81][2048] fp32 -> a_txt [640][2048] bf16 (row b*80+j, j<77, pad 0)
//                              a_ip  [128][2048] bf16 (row b*4+j, j<4, pad 0)
__global__ void pack_enc(const float* __restrict__ enc, bf16_t* __restrict__ a_txt,
                         bf16_t* __restrict__ a_ip)
{
  const long t4 = ((long)blockIdx.x * 256 + threadIdx.x) * 4;
  const long NTXT = 640L * 2048;
  bf16x4 r;
  r[0] = r[1] = r[2] = r[3] = (bf16_t)0.f;
  if (t4 < NTXT) {
    const int row = (int)(t4 >> 11), col = (int)(t4 & 2047);
    const int b = row / 80, j = row - b * 80;
    if (j < TXT_) {
      const float4 v = *(const float4*)(enc + (((long)(b * 81 + j)) << 11) + col);
      r[0] = (bf16_t)v.x; r[1] = (bf16_t)v.y; r[2] = (bf16_t)v.z; r[3] = (bf16_t)v.w;
    }
    *(bf16x4*)(a_txt + t4) = r;
  } else {
    const long u = t4 - NTXT;
    const int row = (int)(u >> 11), col = (int)(u & 2047);
    if (row < 32) {
      const int b = row >> 2, j = row & 3;
      const float4 v = *(const float4*)(enc + (((long)(b * 81 + TXT_ + j)) << 11) + col);
      r[0] = (bf16_t)v.x; r[1] = (bf16_t)v.y; r[2] = (bf16_t)v.z; r[3] = (bf16_t)v.w;
    }
    *(bf16x4*)(a_ip + u) = r;
  }
}

// ---------------------------------------------------------------------------
extern "C" void kernel_launch(void* const* d_in, const int* in_sizes, int n_in,
                              void* d_out, int out_size, void* d_ws, size_t ws_size,
                              hipStream_t stream)
{
  (void)in_sizes; (void)n_in; (void)out_size; (void)ws_size;
  const float* hs  = (const float*)d_in[0];
  const float* enc = (const float*)d_in[1];
  const float* Wq  = (const float*)d_in[2];
  const float* Wk  = (const float*)d_in[3];
  const float* Wv  = (const float*)d_in[4];
  const float* Wki = (const float*)d_in[5];
  const float* Wvi = (const float*)d_in[6];
  const float* Wo  = (const float*)d_in[7];
  const float* bo  = (const float*)d_in[8];

  char* ws = (char*)d_ws;
  size_t off = 0;
  auto alloc = [&](size_t bytes) {
    char* p = ws + off;
    off += (bytes + 255) & ~(size_t)255;
    return p;
  };
  bf16_t* buf1   = (bf16_t*)alloc(83886080);  // hs_bf16, reused as attn_out
  bf16_t* qb     = (bf16_t*)alloc(83886080);  // Q (32768 x 1280)
  bf16_t* Wq_t   = (bf16_t*)alloc(3276800);   // 1280 x 1280
  bf16_t* Wo_t   = (bf16_t*)alloc(3276800);
  bf16_t* Wkv_t  = (bf16_t*)alloc(10485760);  // 2560 x 2048
  bf16_t* Wip_t  = (bf16_t*)alloc(10485760);
  bf16_t* a_txt  = (bf16_t*)alloc(2621440);   // 640 x 2048
  bf16_t* a_ip   = (bf16_t*)alloc(524288);    // 128 x 2048
  bf16_t* kv_txt = (bf16_t*)alloc(3276800);   // 640 x 2560
  bf16_t* kv_ip  = (bf16_t*)alloc(655360);    // 128 x 2560

  const dim3 tb(32, 8);
  cvt_bf16<<<40960, 256, 0, stream>>>(hs, buf1, 41943040L);
  transpose_cvt<<<dim3(40, 40), tb, 0, stream>>>(Wq, Wq_t, 1280, 1280, 1280);
  transpose_cvt<<<dim3(40, 40), tb, 0, stream>>>(Wo, Wo_t, 1280, 1280, 1280);
  transpose_cvt<<<dim3(64, 40), tb, 0, stream>>>(Wk, Wkv_t, 2048, 1280, 2048);
  transpose_cvt<<<dim3(64, 40), tb, 0, stream>>>(Wv, Wkv_t + (long)1280 * 2048, 2048, 1280, 2048);
  transpose_cvt<<<dim3(64, 40), tb, 0, stream>>>(Wki, Wip_t, 2048, 1280, 2048);
  transpose_cvt<<<dim3(64, 40), tb, 0, stream>>>(Wvi, Wip_t + (long)1280 * 2048, 2048, 1280, 2048);
  pack_enc<<<1536, 256, 0, stream>>>(enc, a_txt, a_ip);

  // Q = hs_bf16 @ Wq
  gemm_bt<0><<<dim3(256, 10), 256, 0, stream>>>(buf1, Wq_t, qb, 32768, 1280, 1280,
                                                nullptr, nullptr);
  // K|V = txt @ [Wk|Wv]
  gemm_bt<0><<<dim3(5, 20), 256, 0, stream>>>(a_txt, Wkv_t, kv_txt, 640, 2560, 2048,
                                              nullptr, nullptr);
  // Kip|Vip = ip @ [Wk_ip|Wv_ip]
  gemm_bt<0><<<dim3(1, 20), 256, 0, stream>>>(a_ip, Wip_t, kv_ip, 128, 2560, 2048,
                                              nullptr, nullptr);

  // fused dual-softmax attention -> buf1 (hs_bf16 no longer needed)
  attn_fused<<<dim3(16, 20, 8), 256, 0, stream>>>(qb, kv_txt, kv_ip, buf1);

  // out = attn @ Wo + bo + residual (fp32)
  gemm_bt<1><<<dim3(256, 10), 256, 0, stream>>>(buf1, Wo_t, d_out, 32768, 1280, 1280,
                                                bo, hs);
}

// Round 3
// 505.841 us; speedup vs baseline: 1.4728x; 1.1408x over previous
//
#include <hip/hip_runtime.h>
#include <hip/hip_bf16.h>
#include <cstdint>
#include <cstddef>

// ---------------------------------------------------------------------------
// IPAttnProcessor: out = (softmax(QK^T)V + softmax(QKip^T)Vip) @ Wo + bo + residual
// B=8 SQ=4096 C=1280 CAD=2048 H=20 D=64 TXT=77 NT=4 IP_SCALE=1
// bf16 MFMA GEMMs (m97 128^2 structure + XCD-chunked N-fast swizzle) +
// fused tiny-K attention (256 q/block, in-place on Q buffer).
// ---------------------------------------------------------------------------

typedef __bf16 bf16_t;
typedef __bf16 bf16x8 __attribute__((ext_vector_type(8)));
typedef __bf16 bf16x4 __attribute__((ext_vector_type(4)));
typedef float  f32x4  __attribute__((ext_vector_type(4)));
typedef unsigned int u32x4 __attribute__((ext_vector_type(4)));

using as3_void  = __attribute__((address_space(3))) void;
using as1_cvoid = const __attribute__((address_space(1))) void;

#define TXT_ 77

__device__ __forceinline__ bf16x8 ld16(const void* p) {
  u32x4 v = *(const u32x4*)p;
  return __builtin_bit_cast(bf16x8, v);
}

// ---------------------------------------------------------------------------
// GEMM: C[M,N] = A[M,K] (bf16 row-major) @ Bt[N,K]^T (bf16 row-major N x K)
// 128x128 tile, BK=32, 256 threads (2x2 waves, 64x64 each). 1D grid, N-fast;
// XCD-chunked swizzle when nwg%8==0 (each XCD: contiguous M-stripe, B L2-hot).
// EPI=0: bf16 store. EPI=2: f32 + bias[col] + bf16 residual[row,col].
// ---------------------------------------------------------------------------
template <int EPI>
__global__ __launch_bounds__(256, 4)
void gemm_bt(const bf16_t* __restrict__ A, const bf16_t* __restrict__ Bt,
             void* __restrict__ Cout, int ntn, int N, int K,
             const float* __restrict__ bias, const void* __restrict__ residual)
{
  __shared__ __align__(16) char smem[2][16384];
  const int tid  = threadIdx.x;
  const int lane = tid & 63;
  const int wid  = tid >> 6;
  const int wm = wid >> 1, wn = wid & 1;

  const int nwg = gridDim.x;
  int g = blockIdx.x;
  if ((nwg & 7) == 0)
    g = (blockIdx.x & 7) * (nwg >> 3) + (blockIdx.x >> 3);
  const long bm = (long)(g / ntn) * 128;
  const long bn = (long)(g % ntn) * 128;

  f32x4 acc[4][4] = {};

  const int srow = lane >> 2;
  const int skb  = (lane & 3) ^ (((lane >> 2) ^ (lane >> 4)) & 3);
  const int NT = K >> 5;

  auto stage = [&](int buf, int kt) {
    const int k0 = kt << 5;
#pragma unroll
    for (int cc = 0; cc < 2; ++cc) {
      const int c = wid + cc * 4;
      const bf16_t* ga = A + (bm + c * 16 + srow) * (long)K + (k0 + skb * 8);
      __builtin_amdgcn_global_load_lds((as1_cvoid*)ga,
                                       (as3_void*)(&smem[buf][c * 1024]), 16, 0, 0);
      const bf16_t* gb = Bt + (bn + c * 16 + srow) * (long)K + (k0 + skb * 8);
      __builtin_amdgcn_global_load_lds((as1_cvoid*)gb,
                                       (as3_void*)(&smem[buf][8192 + c * 1024]), 16, 0, 0);
    }
  };

  const int rkb    = (((lane >> 4) ^ (lane & 3) ^ ((lane >> 2) & 3)) & 3) << 4;
  const int rrow_a = wm * 64 + (lane & 15);
  const int rrow_b = wn * 64 + (lane & 15);

  stage(0, 0);
  int cur = 0;
  for (int t = 0; t < NT; ++t) {
    __syncthreads();
    if (t + 1 < NT) stage(cur ^ 1, t + 1);
    const char* sa = smem[cur];
    const char* sb = smem[cur] + 8192;
    bf16x8 af[4], bfv[4];
#pragma unroll
    for (int m = 0; m < 4; ++m)
      af[m] = ld16(sa + (rrow_a + m * 16) * 64 + rkb);
#pragma unroll
    for (int n = 0; n < 4; ++n)
      bfv[n] = ld16(sb + (rrow_b + n * 16) * 64 + rkb);
#pragma unroll
    for (int m = 0; m < 4; ++m)
#pragma unroll
      for (int n = 0; n < 4; ++n)
        acc[m][n] = __builtin_amdgcn_mfma_f32_16x16x32_bf16(af[m], bfv[n], acc[m][n], 0, 0, 0);
    cur ^= 1;
  }

  const int orow0 = wm * 64 + ((lane >> 4) << 2);
  const int ocol0 = wn * 64 + (lane & 15);
#pragma unroll
  for (int m = 0; m < 4; ++m) {
#pragma unroll
    for (int n = 0; n < 4; ++n) {
      const long col = bn + ocol0 + n * 16;
#pragma unroll
      for (int r = 0; r < 4; ++r) {
        const long row = bm + orow0 + m * 16 + r;
        if constexpr (EPI == 0) {
          ((bf16_t*)Cout)[row * N + col] = (bf16_t)acc[m][n][r];
        } else {
          ((float*)Cout)[row * N + col] =
              acc[m][n][r] + bias[col] +
              (float)((const bf16_t*)residual)[row * N + col];
        }
      }
    }
  }
}

// ---------------------------------------------------------------------------
// Fused attention. Block = one (b,h) x 256 q-rows; wave w owns rows [w*64,w*64+64)
// as 4 m-steps of 16. K/V staged ONCE per block (vectorized, XOR-swizzled).
// P (pre-divided by denom) in per-wave LDS [16][128]: keys 0..76 txt, 96..99 ip,
// rest zero -> single 128-key PV accumulation = out_txt + IP_SCALE*out_ip.
// Writes IN-PLACE over the Q buffer (each block rewrites exactly the Q rows/cols
// it preloaded; all Q fragments are in registers before the first store).
// ---------------------------------------------------------------------------
__global__ __launch_bounds__(256, 3)
void attn_fused(const bf16_t* __restrict__ q, const bf16_t* __restrict__ kvt,
                const bf16_t* __restrict__ kvip, bf16_t* __restrict__ outp)
{
  __shared__ __align__(16) bf16_t K_lds[80 * 64];     // [j][d], 128B rows, swz
  __shared__ __align__(16) bf16_t Kip_lds[16 * 64];   // [j][d], swz
  __shared__ __align__(16) bf16_t Vt_lds[64 * 128];   // [d][key], 256B rows, swz
  __shared__ __align__(16) bf16_t P_lds[4][16 * 128]; // per-wave [row][key], swz

  const int tid = threadIdx.x, lane = tid & 63, wid = tid >> 6;
  const int h = blockIdx.y, b = blockIdx.z;
  const int kvcol = h << 6;

  // ---- staging (16B loads; swizzled writes) ----
  for (int idx = tid; idx < 640; idx += 256) {        // K: 80 rows x 8 chunks
    const int j = idx >> 3, c = idx & 7;
    bf16x8 v = {};
    if (j < TXT_) v = ld16(kvt + (long)(b * 80 + j) * 2560 + kvcol + c * 8);
    *(bf16x8*)((char*)K_lds + j * 128 + ((c ^ (j & 7)) << 4)) = v;
  }
  if (tid < 128) {                                    // Kip: 16 rows x 8 chunks
    const int j = tid >> 3, c = tid & 7;
    bf16x8 v = {};
    if (j < 4) v = ld16(kvip + (long)(b * 4 + j) * 2560 + kvcol + c * 8);
    *(bf16x8*)((char*)Kip_lds + j * 128 + ((c ^ (j & 7)) << 4)) = v;
  }
  for (int idx = tid; idx < 1024; idx += 256) {       // V^T: 128 keys x 8 d-chunks
    const int key = idx >> 3, c = idx & 7;
    bf16x8 v = {};
    if (key < TXT_)
      v = ld16(kvt + (long)(b * 80 + key) * 2560 + 1280 + kvcol + c * 8);
    else if (key >= 96 && key < 100)
      v = ld16(kvip + (long)(b * 4 + key - 96) * 2560 + 1280 + kvcol + c * 8);
#pragma unroll
    for (int e = 0; e < 8; ++e) {
      const int d = c * 8 + e;
      *(bf16_t*)((char*)Vt_lds + d * 256 + ((key * 2) ^ ((d & 7) << 4))) = v[e];
    }
  }
  for (int idx = tid; idx < 1024; idx += 256)         // P zero (16KB)
    *(bf16x8*)((char*)P_lds + idx * 16) = (bf16x8){};
  __syncthreads();

  const int l15 = lane & 15, hi = lane >> 4;
  const int dblk = hi << 3;
  const int prow0 = hi << 2;
  const float scale = 0.125f; // 1/sqrt(64)
  char* const pw = (char*)P_lds[wid];

  // preload Q fragments for all 4 m-steps (A-frag: row=lane&15, k=hi*8+i)
  const long qrow0 = (long)b * 4096 + ((long)blockIdx.x << 8) + (wid << 6);
  bf16x8 qf[4][2];
#pragma unroll
  for (int ms = 0; ms < 4; ++ms) {
    const bf16_t* qp = q + (qrow0 + ms * 16 + l15) * 1280 + kvcol;
    qf[ms][0] = ld16(qp + dblk);
    qf[ms][1] = ld16(qp + 32 + dblk);
  }

#pragma unroll
  for (int ms = 0; ms < 4; ++ms) {
    // QK^T over 5 key tiles of 16 (keys >=77 masked after)
    f32x4 sc[5];
#pragma unroll
    for (int t = 0; t < 5; ++t) {
      const int j = (t << 4) + l15;
      const bf16x8 k0 = ld16((char*)K_lds + j * 128 + ((hi ^ (j & 7)) << 4));
      const bf16x8 k1 = ld16((char*)K_lds + j * 128 + (((4 + hi) ^ (j & 7)) << 4));
      f32x4 z = {0.f, 0.f, 0.f, 0.f};
      z = __builtin_amdgcn_mfma_f32_16x16x32_bf16(qf[ms][0], k0, z, 0, 0, 0);
      z = __builtin_amdgcn_mfma_f32_16x16x32_bf16(qf[ms][1], k1, z, 0, 0, 0);
      sc[t] = z;
    }
#pragma unroll
    for (int t = 0; t < 5; ++t) {
      const bool valid = ((t << 4) + l15) < TXT_;
#pragma unroll
      for (int r = 0; r < 4; ++r)
        sc[t][r] = valid ? sc[t][r] * scale : -1e30f;
    }

    // txt softmax per q-row (row=hi*4+r; keys on l15 x 5 tiles), P /= denom
#pragma unroll
    for (int r = 0; r < 4; ++r) {
      float m = sc[0][r];
#pragma unroll
      for (int t = 1; t < 5; ++t) m = fmaxf(m, sc[t][r]);
      m = fmaxf(m, __shfl_xor(m, 1));
      m = fmaxf(m, __shfl_xor(m, 2));
      m = fmaxf(m, __shfl_xor(m, 4));
      m = fmaxf(m, __shfl_xor(m, 8));
      float l = 0.f;
#pragma unroll
      for (int t = 0; t < 5; ++t) { const float p = __expf(sc[t][r] - m); sc[t][r] = p; l += p; }
      l += __shfl_xor(l, 1);
      l += __shfl_xor(l, 2);
      l += __shfl_xor(l, 4);
      l += __shfl_xor(l, 8);
      const float inv = 1.f / l;
      const int row = prow0 + r;
#pragma unroll
      for (int t = 0; t < 5; ++t)
        *(bf16_t*)(pw + row * 256 + ((((t << 4) + l15) * 2) ^ ((row & 7) << 4))) =
            (bf16_t)(sc[t][r] * inv);
    }

    // IP attention (4 keys; l15>=4 masked), separate softmax, keys 96..99
    {
      const bf16x8 ki0 = ld16((char*)Kip_lds + l15 * 128 + ((hi ^ (l15 & 7)) << 4));
      const bf16x8 ki1 = ld16((char*)Kip_lds + l15 * 128 + (((4 + hi) ^ (l15 & 7)) << 4));
      f32x4 z = {0.f, 0.f, 0.f, 0.f};
      z = __builtin_amdgcn_mfma_f32_16x16x32_bf16(qf[ms][0], ki0, z, 0, 0, 0);
      z = __builtin_amdgcn_mfma_f32_16x16x32_bf16(qf[ms][1], ki1, z, 0, 0, 0);
      const bool vip = l15 < 4;
#pragma unroll
      for (int r = 0; r < 4; ++r) {
        const float s = vip ? z[r] * scale : -1e30f;
        float m = s;
        m = fmaxf(m, __shfl_xor(m, 1));
        m = fmaxf(m, __shfl_xor(m, 2));
        m = fmaxf(m, __shfl_xor(m, 4));
        m = fmaxf(m, __shfl_xor(m, 8));
        const float p = __expf(s - m);
        float l = p;
        l += __shfl_xor(l, 1);
        l += __shfl_xor(l, 2);
        l += __shfl_xor(l, 4);
        l += __shfl_xor(l, 8);
        const int row = prow0 + r;
        *(bf16_t*)(pw + row * 256 + (((96 + l15) * 2) ^ ((row & 7) << 4))) =
            (bf16_t)(p * (1.f / l) /* *IP_SCALE==1 */);
      }
    }

    // PV: O[16 x 64] = P[16 x 128] @ Vt^T, 4 k-steps x 4 n-tiles
    f32x4 o[4] = {};
#pragma unroll
    for (int s = 0; s < 4; ++s) {
      const bf16x8 pa =
          ld16(pw + l15 * 256 + ((((s << 2) + hi) << 4) ^ ((l15 & 7) << 4)));
#pragma unroll
      for (int n = 0; n < 4; ++n) {
        const int d = (n << 4) + l15;
        const bf16x8 vb =
            ld16((char*)Vt_lds + d * 256 + ((((s << 2) + hi) << 4) ^ ((d & 7) << 4)));
        o[n] = __builtin_amdgcn_mfma_f32_16x16x32_bf16(pa, vb, o[n], 0, 0, 0);
      }
    }

    const long orow = qrow0 + ms * 16 + prow0;
#pragma unroll
    for (int n = 0; n < 4; ++n)
#pragma unroll
      for (int r = 0; r < 4; ++r)
        outp[(orow + r) * 1280 + kvcol + (n << 4) + l15] = (bf16_t)o[n][r];
  }
}

// ---------------------------------------------------------------------------
// Utility kernels
// ---------------------------------------------------------------------------
__global__ void cvt_bf16(const float* __restrict__ in, bf16_t* __restrict__ out, long n)
{
  const long i = ((long)blockIdx.x * 256 + threadIdx.x) * 4;
  if (i >= n) return;
  const float4 v = *(const float4*)(in + i);
  bf16x4 r;
  r[0] = (bf16_t)v.x; r[1] = (bf16_t)v.y; r[2] = (bf16_t)v.z; r[3] = (bf16_t)v.w;
  *(bf16x4*)(out + i) = r;
}

// in: K x N fp32 -> out: N x K bf16 (row stride ostride)
__global__ void transpose_cvt(const float* __restrict__ in, bf16_t* __restrict__ out,
                              int K, int N, int ostride)
{
  __shared__ float tile[32][33];
  const int k0 = blockIdx.x * 32, n0 = blockIdx.y * 32;
  for (int i = threadIdx.y; i < 32; i += 8)
    tile[i][threadIdx.x] = in[(long)(k0 + i) * N + n0 + threadIdx.x];
  __syncthreads();
  for (int i = threadIdx.y; i < 32; i += 8)
    out[(long)(n0 + i) * ostride + k0 + threadIdx.x] = (bf16_t)tile[threadIdx.x][i];
}

// encoder [8][81][2048] fp32 -> a_txt [640][2048] bf16 (row b*80+j, j<77, pad 0)
//                              a_ip  [128][2048] bf16 (row b*4+j, j<4, pad 0)
__global__ void pack_enc(const float* __restrict__ enc, bf16_t* __restrict__ a_txt,
                         bf16_t* __restrict__ a_ip)
{
  const long t4 = ((long)blockIdx.x * 256 + threadIdx.x) * 4;
  const long NTXT = 640L * 2048;
  bf16x4 r;
  r[0] = r[1] = r[2] = r[3] = (bf16_t)0.f;
  if (t4 < NTXT) {
    const int row = (int)(t4 >> 11), col = (int)(t4 & 2047);
    const int b = row / 80, j = row - b * 80;
    if (j < TXT_) {
      const float4 v = *(const float4*)(enc + (((long)(b * 81 + j)) << 11) + col);
      r[0] = (bf16_t)v.x; r[1] = (bf16_t)v.y; r[2] = (bf16_t)v.z; r[3] = (bf16_t)v.w;
    }
    *(bf16x4*)(a_txt + t4) = r;
  } else {
    const long u = t4 - NTXT;
    const int row = (int)(u >> 11), col = (int)(u & 2047);
    if (row < 32) {
      const int b = row >> 2, j = row & 3;
      const float4 v = *(const float4*)(enc + (((long)(b * 81 + TXT_ + j)) << 11) + col);
      r[0] = (bf16_t)v.x; r[1] = (bf16_t)v.y; r[2] = (bf16_t)v.z; r[3] = (bf16_t)v.w;
    }
    *(bf16x4*)(a_ip + u) = r;
  }
}

// ---------------------------------------------------------------------------
extern "C" void kernel_launch(void* const* d_in, const int* in_sizes, int n_in,
                              void* d_out, int out_size, void* d_ws, size_t ws_size,
                              hipStream_t stream)
{
  (void)in_sizes; (void)n_in; (void)out_size; (void)ws_size;
  const float* hs  = (const float*)d_in[0];
  const float* enc = (const float*)d_in[1];
  const float* Wq  = (const float*)d_in[2];
  const float* Wk  = (const float*)d_in[3];
  const float* Wv  = (const float*)d_in[4];
  const float* Wki = (const float*)d_in[5];
  const float* Wvi = (const float*)d_in[6];
  const float* Wo  = (const float*)d_in[7];
  const float* bo  = (const float*)d_in[8];

  char* ws = (char*)d_ws;
  size_t off = 0;
  auto alloc = [&](size_t bytes) {
    char* p = ws + off;
    off += (bytes + 255) & ~(size_t)255;
    return p;
  };
  bf16_t* buf1   = (bf16_t*)alloc(83886080);  // hs_bf16 (A of GEMM1 + residual of GEMM2)
  bf16_t* qb     = (bf16_t*)alloc(83886080);  // Q (32768 x 1280), attn writes in-place
  bf16_t* Wq_t   = (bf16_t*)alloc(3276800);   // 1280 x 1280
  bf16_t* Wo_t   = (bf16_t*)alloc(3276800);
  bf16_t* Wkv_t  = (bf16_t*)alloc(10485760);  // 2560 x 2048
  bf16_t* Wip_t  = (bf16_t*)alloc(10485760);
  bf16_t* a_txt  = (bf16_t*)alloc(2621440);   // 640 x 2048
  bf16_t* a_ip   = (bf16_t*)alloc(524288);    // 128 x 2048
  bf16_t* kv_txt = (bf16_t*)alloc(3276800);   // 640 x 2560
  bf16_t* kv_ip  = (bf16_t*)alloc(655360);    // 128 x 2560

  const dim3 tb(32, 8);
  cvt_bf16<<<40960, 256, 0, stream>>>(hs, buf1, 41943040L);
  transpose_cvt<<<dim3(40, 40), tb, 0, stream>>>(Wq, Wq_t, 1280, 1280, 1280);
  transpose_cvt<<<dim3(40, 40), tb, 0, stream>>>(Wo, Wo_t, 1280, 1280, 1280);
  transpose_cvt<<<dim3(64, 40), tb, 0, stream>>>(Wk, Wkv_t, 2048, 1280, 2048);
  transpose_cvt<<<dim3(64, 40), tb, 0, stream>>>(Wv, Wkv_t + (long)1280 * 2048, 2048, 1280, 2048);
  transpose_cvt<<<dim3(64, 40), tb, 0, stream>>>(Wki, Wip_t, 2048, 1280, 2048);
  transpose_cvt<<<dim3(64, 40), tb, 0, stream>>>(Wvi, Wip_t + (long)1280 * 2048, 2048, 1280, 2048);
  pack_enc<<<1536, 256, 0, stream>>>(enc, a_txt, a_ip);

  // Q = hs_bf16 @ Wq   (2560 blocks, XCD-chunked N-fast swizzle)
  gemm_bt<0><<<2560, 256, 0, stream>>>(buf1, Wq_t, qb, 10, 1280, 1280,
                                       nullptr, nullptr);
  // K|V = txt @ [Wk|Wv]
  gemm_bt<0><<<100, 256, 0, stream>>>(a_txt, Wkv_t, kv_txt, 20, 2560, 2048,
                                      nullptr, nullptr);
  // Kip|Vip = ip @ [Wk_ip|Wv_ip]
  gemm_bt<0><<<20, 256, 0, stream>>>(a_ip, Wip_t, kv_ip, 20, 2560, 2048,
                                     nullptr, nullptr);

  // fused dual-softmax attention, in-place on qb
  attn_fused<<<dim3(16, 20, 8), 256, 0, stream>>>(qb, kv_txt, kv_ip, qb);

  // out = attn @ Wo + bo + residual(bf16)
  gemm_bt<2><<<2560, 256, 0, stream>>>(qb, Wo_t, d_out, 10, 1280, 1280,
                                       bo, buf1);
}

// Round 4
// 484.825 us; speedup vs baseline: 1.5366x; 1.0433x over previous
//
#include <hip/hip_runtime.h>
#include <hip/hip_bf16.h>
#include <cstdint>
#include <cstddef>

// ---------------------------------------------------------------------------
// IPAttnProcessor: out = (softmax(QK^T)V + softmax(QKip^T)Vip) @ Wo + bo + residual
// B=8 SQ=4096 C=1280 CAD=2048 H=20 D=64 TXT=77 NT=4 IP_SCALE=1
// Big GEMMs: 256^2-tile 8-wave counted-vmcnt pipeline (T2+T3+T4+T5, ring-4 LDS).
// Small GEMMs: m97 128^2 structure. Fused tiny-K attention (in-place on Q).
// ---------------------------------------------------------------------------

typedef __bf16 bf16_t;
typedef __bf16 bf16x8 __attribute__((ext_vector_type(8)));
typedef __bf16 bf16x4 __attribute__((ext_vector_type(4)));
typedef float  f32x4  __attribute__((ext_vector_type(4)));
typedef unsigned int u32x4 __attribute__((ext_vector_type(4)));

using as3_void  = __attribute__((address_space(3))) void;
using as1_cvoid = const __attribute__((address_space(1))) void;

#define TXT_ 77

__device__ __forceinline__ bf16x8 ld16(const void* p) {
  u32x4 v = *(const u32x4*)p;
  return __builtin_bit_cast(bf16x8, v);
}

// ---------------------------------------------------------------------------
// Big GEMM: C[M,N] = A[M,K] @ Bt[N,K]^T, 256x256 tile, BK=32, 512 threads
// (8 waves = 2M x 4N, each 128x64 out). LDS: ring of 4 K-tile buffers
// (A 16KB + B 16KB each) = 128KB. Staging targets t+2 (never a buffer in use)
// -> one barrier + vmcnt(4) per K-tile (counted, non-draining; T4).
// Swizzle: phys_c16 = c16 ^ ((row>>1)&3), pre-swizzled global source (T2).
// EPI=0: bf16 store. EPI=2: f32 + bias[col] + bf16 residual.
// ---------------------------------------------------------------------------
template <int EPI>
__global__ __launch_bounds__(512, 2)
void gemm256(const bf16_t* __restrict__ A, const bf16_t* __restrict__ Bt,
             void* __restrict__ Cout, int ntn, int N, int K,
             const float* __restrict__ bias, const void* __restrict__ residual)
{
  __shared__ __align__(16) char smem[131072]; // A ring @0 (4x16KB), B ring @64KB
  const int tid = threadIdx.x, lane = tid & 63, wid = tid >> 6;
  const int wm = wid >> 2, wn = wid & 3;

  const int nwg = gridDim.x;
  int g = blockIdx.x;
  if ((nwg & 7) == 0) g = (blockIdx.x & 7) * (nwg >> 3) + (blockIdx.x >> 3);
  const long bm = (long)(g / ntn) * 256;
  const long bn = (long)(g % ntn) * 256;

  const int NTk = K >> 5;

  // staging: lane -> row = ci*16 + (lane>>2); fetch logical col chunk
  // (lane&3)^((lane>>3)&3) so linear LDS holds the read-side swizzle.
  const int srow = lane >> 2;
  const int scol = ((lane & 3) ^ ((lane >> 3) & 3)) * 8;

  auto stageA = [&](int t) {
    const int buf = t & 3;
    const long k0 = (long)t << 5;
#pragma unroll
    for (int j = 0; j < 2; ++j) {
      const int ci = j * 8 + wid;
      const bf16_t* gp = A + (bm + ci * 16 + srow) * (long)K + k0 + scol;
      __builtin_amdgcn_global_load_lds((as1_cvoid*)gp,
          (as3_void*)(smem + buf * 16384 + ci * 1024), 16, 0, 0);
    }
  };
  auto stageB = [&](int t) {
    const int buf = t & 3;
    const long k0 = (long)t << 5;
#pragma unroll
    for (int j = 0; j < 2; ++j) {
      const int ci = j * 8 + wid;
      const bf16_t* gp = Bt + (bn + ci * 16 + srow) * (long)K + k0 + scol;
      __builtin_amdgcn_global_load_lds((as1_cvoid*)gp,
          (as3_void*)(smem + 65536 + buf * 16384 + ci * 1024), 16, 0, 0);
    }
  };

  const int l15 = lane & 15, kq = lane >> 4;
  const int rc16 = (kq ^ ((l15 >> 1) & 3)) << 4; // read-side swizzled 16B chunk

  f32x4 acc[8][4] = {};

  // prologue: K-tiles 0,1 staged; wait for tile 0 (4 newest = tile 1 in flight)
  stageA(0); stageB(0); stageA(1); stageB(1);
  asm volatile("s_waitcnt vmcnt(4)" ::: "memory");
  __builtin_amdgcn_s_barrier();

  for (int t = 0; t < NTk; ++t) {
    const char* sa = smem + (t & 3) * 16384;
    const char* sb = smem + 65536 + (t & 3) * 16384;
    bf16x8 bfr[4], afr[4];
    // ---- phase 0: B all + A m0-3, stage A(t+2), MFMA upper half ----
#pragma unroll
    for (int n = 0; n < 4; ++n)
      bfr[n] = ld16(sb + (wn * 64 + n * 16 + l15) * 64 + rc16);
#pragma unroll
    for (int m = 0; m < 4; ++m)
      afr[m] = ld16(sa + (wm * 128 + m * 16 + l15) * 64 + rc16);
    if (t + 2 < NTk) stageA(t + 2);
    __builtin_amdgcn_s_setprio(1);
#pragma unroll
    for (int m = 0; m < 4; ++m)
#pragma unroll
      for (int n = 0; n < 4; ++n)
        acc[m][n] = __builtin_amdgcn_mfma_f32_16x16x32_bf16(afr[m], bfr[n], acc[m][n], 0, 0, 0);
    __builtin_amdgcn_s_setprio(0);
    // ---- phase 1: A m4-7, stage B(t+2), MFMA lower half ----
#pragma unroll
    for (int m = 0; m < 4; ++m)
      afr[m] = ld16(sa + (wm * 128 + (m + 4) * 16 + l15) * 64 + rc16);
    if (t + 2 < NTk) stageB(t + 2);
    __builtin_amdgcn_s_setprio(1);
#pragma unroll
    for (int m = 0; m < 4; ++m)
#pragma unroll
      for (int n = 0; n < 4; ++n)
        acc[m + 4][n] = __builtin_amdgcn_mfma_f32_16x16x32_bf16(afr[m], bfr[n], acc[m + 4][n], 0, 0, 0);
    __builtin_amdgcn_s_setprio(0);
    // ---- publish staged tile t+1 (counted vmcnt; drain only at NTk-2) ----
    if (t == NTk - 2) asm volatile("s_waitcnt vmcnt(0)" ::: "memory");
    else              asm volatile("s_waitcnt vmcnt(4)" ::: "memory");
    __builtin_amdgcn_s_barrier();
    asm volatile("" ::: "memory");
  }

  const int orow0 = (lane >> 4) << 2;
#pragma unroll
  for (int m = 0; m < 8; ++m) {
#pragma unroll
    for (int n = 0; n < 4; ++n) {
      const long col = bn + wn * 64 + n * 16 + l15;
#pragma unroll
      for (int r = 0; r < 4; ++r) {
        const long row = bm + wm * 128 + m * 16 + orow0 + r;
        if constexpr (EPI == 0) {
          ((bf16_t*)Cout)[row * N + col] = (bf16_t)acc[m][n][r];
        } else {
          ((float*)Cout)[row * N + col] =
              acc[m][n][r] + bias[col] +
              (float)((const bf16_t*)residual)[row * N + col];
        }
      }
    }
  }
}

// ---------------------------------------------------------------------------
// Small GEMM (m97 128^2 structure), used for K/V projections.
// ---------------------------------------------------------------------------
__global__ __launch_bounds__(256, 4)
void gemm_bt(const bf16_t* __restrict__ A, const bf16_t* __restrict__ Bt,
             bf16_t* __restrict__ Cout, int ntn, int N, int K)
{
  __shared__ __align__(16) char smem[2][16384];
  const int tid  = threadIdx.x;
  const int lane = tid & 63;
  const int wid  = tid >> 6;
  const int wm = wid >> 1, wn = wid & 1;

  const int g = blockIdx.x;
  const long bm = (long)(g / ntn) * 128;
  const long bn = (long)(g % ntn) * 128;

  f32x4 acc[4][4] = {};

  const int srow = lane >> 2;
  const int skb  = (lane & 3) ^ (((lane >> 2) ^ (lane >> 4)) & 3);
  const int NT = K >> 5;

  auto stage = [&](int buf, int kt) {
    const int k0 = kt << 5;
#pragma unroll
    for (int cc = 0; cc < 2; ++cc) {
      const int c = wid + cc * 4;
      const bf16_t* ga = A + (bm + c * 16 + srow) * (long)K + (k0 + skb * 8);
      __builtin_amdgcn_global_load_lds((as1_cvoid*)ga,
                                       (as3_void*)(&smem[buf][c * 1024]), 16, 0, 0);
      const bf16_t* gb = Bt + (bn + c * 16 + srow) * (long)K + (k0 + skb * 8);
      __builtin_amdgcn_global_load_lds((as1_cvoid*)gb,
                                       (as3_void*)(&smem[buf][8192 + c * 1024]), 16, 0, 0);
    }
  };

  const int rkb    = (((lane >> 4) ^ (lane & 3) ^ ((lane >> 2) & 3)) & 3) << 4;
  const int rrow_a = wm * 64 + (lane & 15);
  const int rrow_b = wn * 64 + (lane & 15);

  stage(0, 0);
  int cur = 0;
  for (int t = 0; t < NT; ++t) {
    __syncthreads();
    if (t + 1 < NT) stage(cur ^ 1, t + 1);
    const char* sa = smem[cur];
    const char* sb = smem[cur] + 8192;
    bf16x8 af[4], bfv[4];
#pragma unroll
    for (int m = 0; m < 4; ++m)
      af[m] = ld16(sa + (rrow_a + m * 16) * 64 + rkb);
#pragma unroll
    for (int n = 0; n < 4; ++n)
      bfv[n] = ld16(sb + (rrow_b + n * 16) * 64 + rkb);
#pragma unroll
    for (int m = 0; m < 4; ++m)
#pragma unroll
      for (int n = 0; n < 4; ++n)
        acc[m][n] = __builtin_amdgcn_mfma_f32_16x16x32_bf16(af[m], bfv[n], acc[m][n], 0, 0, 0);
    cur ^= 1;
  }

  const int orow0 = wm * 64 + ((lane >> 4) << 2);
  const int ocol0 = wn * 64 + (lane & 15);
#pragma unroll
  for (int m = 0; m < 4; ++m)
#pragma unroll
    for (int n = 0; n < 4; ++n) {
      const long col = bn + ocol0 + n * 16;
#pragma unroll
      for (int r = 0; r < 4; ++r)
        Cout[(bm + orow0 + m * 16 + r) * (long)N + col] = (bf16_t)acc[m][n][r];
    }
}

// ---------------------------------------------------------------------------
// Fused attention (unchanged from round 3; writes in-place over Q).
// ---------------------------------------------------------------------------
__global__ __launch_bounds__(256, 3)
void attn_fused(const bf16_t* __restrict__ q, const bf16_t* __restrict__ kvt,
                const bf16_t* __restrict__ kvip, bf16_t* __restrict__ outp)
{
  __shared__ __align__(16) bf16_t K_lds[80 * 64];
  __shared__ __align__(16) bf16_t Kip_lds[16 * 64];
  __shared__ __align__(16) bf16_t Vt_lds[64 * 128];
  __shared__ __align__(16) bf16_t P_lds[4][16 * 128];

  const int tid = threadIdx.x, lane = tid & 63, wid = tid >> 6;
  const int h = blockIdx.y, b = blockIdx.z;
  const int kvcol = h << 6;

  for (int idx = tid; idx < 640; idx += 256) {
    const int j = idx >> 3, c = idx & 7;
    bf16x8 v = {};
    if (j < TXT_) v = ld16(kvt + (long)(b * 80 + j) * 2560 + kvcol + c * 8);
    *(bf16x8*)((char*)K_lds + j * 128 + ((c ^ (j & 7)) << 4)) = v;
  }
  if (tid < 128) {
    const int j = tid >> 3, c = tid & 7;
    bf16x8 v = {};
    if (j < 4) v = ld16(kvip + (long)(b * 4 + j) * 2560 + kvcol + c * 8);
    *(bf16x8*)((char*)Kip_lds + j * 128 + ((c ^ (j & 7)) << 4)) = v;
  }
  for (int idx = tid; idx < 1024; idx += 256) {
    const int key = idx >> 3, c = idx & 7;
    bf16x8 v = {};
    if (key < TXT_)
      v = ld16(kvt + (long)(b * 80 + key) * 2560 + 1280 + kvcol + c * 8);
    else if (key >= 96 && key < 100)
      v = ld16(kvip + (long)(b * 4 + key - 96) * 2560 + 1280 + kvcol + c * 8);
#pragma unroll
    for (int e = 0; e < 8; ++e) {
      const int d = c * 8 + e;
      *(bf16_t*)((char*)Vt_lds + d * 256 + ((key * 2) ^ ((d & 7) << 4))) = v[e];
    }
  }
  for (int idx = tid; idx < 1024; idx += 256)
    *(bf16x8*)((char*)P_lds + idx * 16) = (bf16x8){};
  __syncthreads();

  const int l15 = lane & 15, hi = lane >> 4;
  const int dblk = hi << 3;
  const int prow0 = hi << 2;
  const float scale = 0.125f;
  char* const pw = (char*)P_lds[wid];

  const long qrow0 = (long)b * 4096 + ((long)blockIdx.x << 8) + (wid << 6);
  bf16x8 qf[4][2];
#pragma unroll
  for (int ms = 0; ms < 4; ++ms) {
    const bf16_t* qp = q + (qrow0 + ms * 16 + l15) * 1280 + kvcol;
    qf[ms][0] = ld16(qp + dblk);
    qf[ms][1] = ld16(qp + 32 + dblk);
  }

#pragma unroll
  for (int ms = 0; ms < 4; ++ms) {
    f32x4 sc[5];
#pragma unroll
    for (int t = 0; t < 5; ++t) {
      const int j = (t << 4) + l15;
      const bf16x8 k0 = ld16((char*)K_lds + j * 128 + ((hi ^ (j & 7)) << 4));
      const bf16x8 k1 = ld16((char*)K_lds + j * 128 + (((4 + hi) ^ (j & 7)) << 4));
      f32x4 z = {0.f, 0.f, 0.f, 0.f};
      z = __builtin_amdgcn_mfma_f32_16x16x32_bf16(qf[ms][0], k0, z, 0, 0, 0);
      z = __builtin_amdgcn_mfma_f32_16x16x32_bf16(qf[ms][1], k1, z, 0, 0, 0);
      sc[t] = z;
    }
#pragma unroll
    for (int t = 0; t < 5; ++t) {
      const bool valid = ((t << 4) + l15) < TXT_;
#pragma unroll
      for (int r = 0; r < 4; ++r)
        sc[t][r] = valid ? sc[t][r] * scale : -1e30f;
    }

#pragma unroll
    for (int r = 0; r < 4; ++r) {
      float m = sc[0][r];
#pragma unroll
      for (int t = 1; t < 5; ++t) m = fmaxf(m, sc[t][r]);
      m = fmaxf(m, __shfl_xor(m, 1));
      m = fmaxf(m, __shfl_xor(m, 2));
      m = fmaxf(m, __shfl_xor(m, 4));
      m = fmaxf(m, __shfl_xor(m, 8));
      float l = 0.f;
#pragma unroll
      for (int t = 0; t < 5; ++t) { const float p = __expf(sc[t][r] - m); sc[t][r] = p; l += p; }
      l += __shfl_xor(l, 1);
      l += __shfl_xor(l, 2);
      l += __shfl_xor(l, 4);
      l += __shfl_xor(l, 8);
      const float inv = 1.f / l;
      const int row = prow0 + r;
#pragma unroll
      for (int t = 0; t < 5; ++t)
        *(bf16_t*)(pw + row * 256 + ((((t << 4) + l15) * 2) ^ ((row & 7) << 4))) =
            (bf16_t)(sc[t][r] * inv);
    }

    {
      const bf16x8 ki0 = ld16((char*)Kip_lds + l15 * 128 + ((hi ^ (l15 & 7)) << 4));
      const bf16x8 ki1 = ld16((char*)Kip_lds + l15 * 128 + (((4 + hi) ^ (l15 & 7)) << 4));
      f32x4 z = {0.f, 0.f, 0.f, 0.f};
      z = __builtin_amdgcn_mfma_f32_16x16x32_bf16(qf[ms][0], ki0, z, 0, 0, 0);
      z = __builtin_amdgcn_mfma_f32_16x16x32_bf16(qf[ms][1], ki1, z, 0, 0, 0);
      const bool vip = l15 < 4;
#pragma unroll
      for (int r = 0; r < 4; ++r) {
        const float s = vip ? z[r] * scale : -1e30f;
        float m = s;
        m = fmaxf(m, __shfl_xor(m, 1));
        m = fmaxf(m, __shfl_xor(m, 2));
        m = fmaxf(m, __shfl_xor(m, 4));
        m = fmaxf(m, __shfl_xor(m, 8));
        const float p = __expf(s - m);
        float l = p;
        l += __shfl_xor(l, 1);
        l += __shfl_xor(l, 2);
        l += __shfl_xor(l, 4);
        l += __shfl_xor(l, 8);
        const int row = prow0 + r;
        *(bf16_t*)(pw + row * 256 + (((96 + l15) * 2) ^ ((row & 7) << 4))) =
            (bf16_t)(p * (1.f / l));
      }
    }

    f32x4 o[4] = {};
#pragma unroll
    for (int s = 0; s < 4; ++s) {
      const bf16x8 pa =
          ld16(pw + l15 * 256 + ((((s << 2) + hi) << 4) ^ ((l15 & 7) << 4)));
#pragma unroll
      for (int n = 0; n < 4; ++n) {
        const int d = (n << 4) + l15;
        const bf16x8 vb =
            ld16((char*)Vt_lds + d * 256 + ((((s << 2) + hi) << 4) ^ ((d & 7) << 4)));
        o[n] = __builtin_amdgcn_mfma_f32_16x16x32_bf16(pa, vb, o[n], 0, 0, 0);
      }
    }

    const long orow = qrow0 + ms * 16 + prow0;
#pragma unroll
    for (int n = 0; n < 4; ++n)
#pragma unroll
      for (int r = 0; r < 4; ++r)
        outp[(orow + r) * 1280 + kvcol + (n << 4) + l15] = (bf16_t)o[n][r];
  }
}

// ---------------------------------------------------------------------------
// Utility kernels
// ---------------------------------------------------------------------------
__global__ void cvt_bf16(const float* __restrict__ in, bf16_t* __restrict__ out, long n)
{
  const long i = ((long)blockIdx.x * 256 + threadIdx.x) * 4;
  if (i >= n) return;
  const float4 v = *(const float4*)(in + i);
  bf16x4 r;
  r[0] = (bf16_t)v.x; r[1] = (bf16_t)v.y; r[2] = (bf16_t)v.z; r[3] = (bf16_t)v.w;
  *(bf16x4*)(out + i) = r;
}

__global__ void transpose_cvt(const float* __restrict__ in, bf16_t* __restrict__ out,
                              int K, int N, int ostride)
{
  __shared__ float tile[32][33];
  const int k0 = blockIdx.x * 32, n0 = blockIdx.y * 32;
  for (int i = threadIdx.y; i < 32; i += 8)
    tile[i][threadIdx.x] = in[(long)(k0 + i) * N + n0 + threadIdx.x];
  __syncthreads();
  for (int i = threadIdx.y; i < 32; i += 8)
    out[(long)(n0 + i) * ostride + k0 + threadIdx.x] = (bf16_t)tile[threadIdx.x][i];
}

__global__ void pack_enc(const float* __restrict__ enc, bf16_t* __restrict__ a_txt,
                         bf16_t* __restrict__ a_ip)
{
  const long t4 = ((long)blockIdx.x * 256 + threadIdx.x) * 4;
  const long NTXT = 640L * 2048;
  bf16x4 r;
  r[0] = r[1] = r[2] = r[3] = (bf16_t)0.f;
  if (t4 < NTXT) {
    const int row = (int)(t4 >> 11), col = (int)(t4 & 2047);
    const int b = row / 80, j = row - b * 80;
    if (j < TXT_) {
      const float4 v = *(const float4*)(enc + (((long)(b * 81 + j)) << 11) + col);
      r[0] = (bf16_t)v.x; r[1] = (bf16_t)v.y; r[2] = (bf16_t)v.z; r[3] = (bf16_t)v.w;
    }
    *(bf16x4*)(a_txt + t4) = r;
  } else {
    const long u = t4 - NTXT;
    const int row = (int)(u >> 11), col = (int)(u & 2047);
    if (row < 32) {
      const int b = row >> 2, j = row & 3;
      const float4 v = *(const float4*)(enc + (((long)(b * 81 + TXT_ + j)) << 11) + col);
      r[0] = (bf16_t)v.x; r[1] = (bf16_t)v.y; r[2] = (bf16_t)v.z; r[3] = (bf16_t)v.w;
    }
    *(bf16x4*)(a_ip + u) = r;
  }
}

// ---------------------------------------------------------------------------
extern "C" void kernel_launch(void* const* d_in, const int* in_sizes, int n_in,
                              void* d_out, int out_size, void* d_ws, size_t ws_size,
                              hipStream_t stream)
{
  (void)in_sizes; (void)n_in; (void)out_size; (void)ws_size;
  const float* hs  = (const float*)d_in[0];
  const float* enc = (const float*)d_in[1];
  const float* Wq  = (const float*)d_in[2];
  const float* Wk  = (const float*)d_in[3];
  const float* Wv  = (const float*)d_in[4];
  const float* Wki = (const float*)d_in[5];
  const float* Wvi = (const float*)d_in[6];
  const float* Wo  = (const float*)d_in[7];
  const float* bo  = (const float*)d_in[8];

  char* ws = (char*)d_ws;
  size_t off = 0;
  auto alloc = [&](size_t bytes) {
    char* p = ws + off;
    off += (bytes + 255) & ~(size_t)255;
    return p;
  };
  bf16_t* buf1   = (bf16_t*)alloc(83886080);  // hs_bf16 (A of GEMM1 + residual of GEMM2)
  bf16_t* qb     = (bf16_t*)alloc(83886080);  // Q (32768 x 1280), attn in-place
  bf16_t* Wq_t   = (bf16_t*)alloc(3276800);
  bf16_t* Wo_t   = (bf16_t*)alloc(3276800);
  bf16_t* Wkv_t  = (bf16_t*)alloc(10485760);
  bf16_t* Wip_t  = (bf16_t*)alloc(10485760);
  bf16_t* a_txt  = (bf16_t*)alloc(2621440);
  bf16_t* a_ip   = (bf16_t*)alloc(524288);
  bf16_t* kv_txt = (bf16_t*)alloc(3276800);
  bf16_t* kv_ip  = (bf16_t*)alloc(655360);

  const dim3 tb(32, 8);
  cvt_bf16<<<40960, 256, 0, stream>>>(hs, buf1, 41943040L);
  transpose_cvt<<<dim3(40, 40), tb, 0, stream>>>(Wq, Wq_t, 1280, 1280, 1280);
  transpose_cvt<<<dim3(40, 40), tb, 0, stream>>>(Wo, Wo_t, 1280, 1280, 1280);
  transpose_cvt<<<dim3(64, 40), tb, 0, stream>>>(Wk, Wkv_t, 2048, 1280, 2048);
  transpose_cvt<<<dim3(64, 40), tb, 0, stream>>>(Wv, Wkv_t + (long)1280 * 2048, 2048, 1280, 2048);
  transpose_cvt<<<dim3(64, 40), tb, 0, stream>>>(Wki, Wip_t, 2048, 1280, 2048);
  transpose_cvt<<<dim3(64, 40), tb, 0, stream>>>(Wvi, Wip_t + (long)1280 * 2048, 2048, 1280, 2048);
  pack_enc<<<1536, 256, 0, stream>>>(enc, a_txt, a_ip);

  // Q = hs_bf16 @ Wq   (256^2 pipeline, XCD-chunked N-fast swizzle, 640 blocks)
  gemm256<0><<<640, 512, 0, stream>>>(buf1, Wq_t, qb, 5, 1280, 1280,
                                      nullptr, nullptr);
  // K|V = txt @ [Wk|Wv]
  gemm_bt<<<100, 256, 0, stream>>>(a_txt, Wkv_t, kv_txt, 20, 2560, 2048);
  // Kip|Vip = ip @ [Wk_ip|Wv_ip]
  gemm_bt<<<20, 256, 0, stream>>>(a_ip, Wip_t, kv_ip, 20, 2560, 2048);

  // fused dual-softmax attention, in-place on qb
  attn_fused<<<dim3(16, 20, 8), 256, 0, stream>>>(qb, kv_txt, kv_ip, qb);

  // out = attn @ Wo + bo + residual(bf16)
  gemm256<2><<<640, 512, 0, stream>>>(qb, Wo_t, d_out, 5, 1280, 1280,
                                      bo, buf1);
}